// Round 3
// baseline (2068.954 us; speedup 1.0000x reference)
//
#include <hip/hip_runtime.h>
#include <cfloat>
#include <cstdint>

#define BATCH 16
#define PRIORS 3000
#define NCLS 201
#define NLBL 200           // NCLS - 1
#define TOPN 100
#define SCORE_THR 0.02f
#define NMS_THR 0.45f
#define PPB 16             // priors per block in score_filter (16 waves)
#define NBLKX ((PRIORS + PPB - 1) / PPB)   // 188

// NMS: scores+oids live in registers. 512 threads x 64 slots = 32768 cap
// (actual n ~= 17.6k/image, +100 sigma margin).
#define NMS_T 512
#define NMS_K 64
#define NMS_CAP (NMS_T * NMS_K)

// ---------------------------------------------------------------------------
// Kernel A: decode boxes, per-image max coordinate (for the class-offset
// trick), zero the per-image candidate counters.
// ---------------------------------------------------------------------------
__global__ __launch_bounds__(256) void decode_kernel(
    const float* __restrict__ deltas,   // [B][P][4]
    const float* __restrict__ priors,   // [P][4]
    float* __restrict__ dec,            // [B][P][4]  (x1,y1,x2,y2, un-offset)
    float* __restrict__ offA,           // [B]        max(dec)+1
    int*   __restrict__ cnt)            // [B]
{
    const int b = blockIdx.x;
    const int tid = threadIdx.x;
    float lmax = -FLT_MAX;
    for (int p = tid; p < PRIORS; p += 256) {
        float4 d4 = ((const float4*)deltas)[(size_t)b * PRIORS + p];
        float4 pr = ((const float4*)priors)[p];
        float cx = d4.x * 0.1f * pr.z + pr.x;
        float cy = d4.y * 0.1f * pr.w + pr.y;
        float w  = expf(d4.z * 0.2f) * pr.z;
        float h  = expf(d4.w * 0.2f) * pr.w;
        float x1 = cx - 0.5f * w, y1 = cy - 0.5f * h;
        float x2 = cx + 0.5f * w, y2 = cy + 0.5f * h;
        ((float4*)dec)[(size_t)b * PRIORS + p] = make_float4(x1, y1, x2, y2);
        lmax = fmaxf(lmax, fmaxf(fmaxf(x1, y1), fmaxf(x2, y2)));
    }
    for (int d = 32; d > 0; d >>= 1)
        lmax = fmaxf(lmax, __shfl_xor(lmax, d, 64));
    __shared__ float wmax[4];
    if ((tid & 63) == 0) wmax[tid >> 6] = lmax;
    __syncthreads();
    if (tid == 0) {
        float m = fmaxf(fmaxf(wmax[0], wmax[1]), fmaxf(wmax[2], wmax[3]));
        offA[b] = m + 1.0f;
        cnt[b] = 0;
    }
}

// ---------------------------------------------------------------------------
// Kernel B: block = 16 waves = 16 priors of ONE image. Per-wave softmax,
// LDS staging, ONE global atomicAdd per block (R1->R2 fix: per-candidate
// global atomics were 300 ns each, serialized -> 5.3 ms).
// areaArr removed (R3): NMS recomputes area from the loaded box bit-exactly.
// ---------------------------------------------------------------------------
__global__ __launch_bounds__(1024) void score_filter_kernel(
    const float*  __restrict__ obj,     // [B][P][NCLS]
    const float*  __restrict__ dec,     // [B][P][4]
    const float*  __restrict__ offA,    // [B]
    int*          __restrict__ cnt,     // [B]
    float*        __restrict__ sArr,    // [B][cap]
    float4*       __restrict__ boxArr,  // [B][cap]  offset boxes
    int*          __restrict__ oidArr,  // [B][cap]  p*200 + (c-1)
    int cap)
{
    __shared__ float lprob[PPB * NLBL];
    __shared__ uint32_t lpc[PPB * NLBL];  // (p<<8) | c
    __shared__ int lcnt;
    __shared__ int gbase;

    const int b    = blockIdx.y;
    const int tid  = threadIdx.x;
    const int wave = tid >> 6;
    const int lane = tid & 63;
    const int p    = blockIdx.x * PPB + wave;

    if (tid == 0) lcnt = 0;
    __syncthreads();

    if (p < PRIORS) {
        const float* x = obj + ((size_t)b * PRIORS + p) * NCLS;
        float v0 = x[lane];
        float v1 = x[lane + 64];
        float v2 = x[lane + 128];
        float v3 = (lane + 192 < NCLS) ? x[lane + 192] : -FLT_MAX;
        float mx = fmaxf(fmaxf(v0, v1), fmaxf(v2, v3));
        for (int d = 32; d > 0; d >>= 1) mx = fmaxf(mx, __shfl_xor(mx, d, 64));
        float e0 = expf(v0 - mx), e1 = expf(v1 - mx), e2 = expf(v2 - mx);
        float e3 = (lane + 192 < NCLS) ? expf(v3 - mx) : 0.0f;
        float se = e0 + e1 + e2 + e3;
        for (int d = 32; d > 0; d >>= 1) se += __shfl_xor(se, d, 64);
        float inv = 1.0f / se;
        float ev[4] = { e0, e1, e2, e3 };
#pragma unroll
        for (int k = 0; k < 4; ++k) {
            int c = lane + 64 * k;
            if (c >= 1 && c < NCLS) {
                float prob = ev[k] * inv;
                if (prob > SCORE_THR) {
                    int li = atomicAdd(&lcnt, 1);        // LDS atomic: cheap
                    lprob[li] = prob;
                    lpc[li]   = ((uint32_t)p << 8) | (uint32_t)c;
                }
            }
        }
    }
    __syncthreads();

    const int nloc = lcnt;
    if (tid == 0 && nloc > 0) gbase = atomicAdd(&cnt[b], nloc);
    __syncthreads();

    if (nloc > 0) {
        const int base = gbase;
        const float ofb = offA[b];
        for (int j = tid; j < nloc; j += 1024) {
            int idx = base + j;
            if (idx >= cap) continue;
            uint32_t pc = lpc[j];
            int pp = (int)(pc >> 8);
            int c  = (int)(pc & 0xff);
            float4 db = ((const float4*)dec)[(size_t)b * PRIORS + pp];
            float lo  = (float)c * ofb;
            float bx1 = db.x + lo, by1 = db.y + lo;
            float bx2 = db.z + lo, by2 = db.w + lo;
            size_t o = (size_t)b * cap + idx;
            sArr[o]   = lprob[j];
            boxArr[o] = make_float4(bx1, by1, bx2, by2);
            oidArr[o] = pp * NLBL + (c - 1);
        }
    }
}

// ---------------------------------------------------------------------------
// Kernel C (v3): one block per image, scores+oids in REGISTERS.
// v2 was 10.4 us/iter, VALUBusy 3% -> latency-chained global loads of s[].
// Now argmax is pure-register + shuffle reduce; sweep updates registers and
// re-reads only boxes (coalesced float4, L2-resident). 2 barriers/iter.
// Tie-break on original flat index == jnp.argmax semantics (bitwise score
// ties DO occur: ~19 expected tied pairs per image at 17.6k candidates).
// ---------------------------------------------------------------------------
__global__ __launch_bounds__(NMS_T, 2) void nms_kernel(
    const float*  __restrict__ dec,
    const int*    __restrict__ cnt,
    const float*  __restrict__ sArr,
    const float4* __restrict__ boxArr,
    const int*    __restrict__ oidArr,
    float*        __restrict__ out,     // [B][TOPN][6]
    int cap)
{
    const int b = blockIdx.x;
    const int tid = threadIdx.x;
    int n = cnt[b]; if (n > cap) n = cap;
    const size_t base = (size_t)b * cap;
    const float*  s   = sArr + base;
    const float4* bx  = boxArr + base;
    const int*    oid = oidArr + base;

    // ---- load candidates into registers (coalesced) ----
    float sreg[NMS_K];
    int   oreg[NMS_K];
#pragma unroll
    for (int k = 0; k < NMS_K; ++k) {
        int j = tid + k * NMS_T;
        bool v = j < n;
        sreg[k] = v ? s[j]   : -2.0f;
        oreg[k] = v ? oid[j] : 0x7fffffff;
    }

    __shared__ float rs[NMS_T / 64]; __shared__ int ro[NMS_T / 64]; __shared__ int rj[NMS_T / 64];
    __shared__ float4 selBox; __shared__ float selArea;
    __shared__ int fjS; __shared__ int stop;

    for (int t = 0; t < TOPN; ++t) {
        // ---- per-thread argmax over registers ----
        float bs = -2.0f; int bo = 0x7fffffff; int bj = 0;
#pragma unroll
        for (int k = 0; k < NMS_K; ++k) {
            float v = sreg[k];
            int o = oreg[k];
            if (v > bs || (v == bs && o < bo)) { bs = v; bo = o; bj = tid + k * NMS_T; }
        }
        // ---- wave reduce ----
        for (int d = 32; d > 0; d >>= 1) {
            float os = __shfl_xor(bs, d, 64);
            int oo = __shfl_xor(bo, d, 64);
            int oj = __shfl_xor(bj, d, 64);
            if (os > bs || (os == bs && oo < bo)) { bs = os; bo = oo; bj = oj; }
        }
        if ((tid & 63) == 0) { int w = tid >> 6; rs[w] = bs; ro[w] = bo; rj[w] = bj; }
        __syncthreads();
        // ---- final reduce + selection bookkeeping (tid 0) ----
        if (tid == 0) {
            float fs = rs[0]; int fo = ro[0]; int fj = rj[0];
            for (int w = 1; w < NMS_T / 64; ++w)
                if (rs[w] > fs || (rs[w] == fs && ro[w] < fo)) { fs = rs[w]; fo = ro[w]; fj = rj[w]; }
            if (fs > SCORE_THR) {
                stop = 0;
                fjS = fj;
                float4 sb = bx[fj];            // L2 hit; issued parallel w/ dec read
                int p = fo / NLBL;
                int c = fo - p * NLBL + 1;
                float4 db = ((const float4*)dec)[(size_t)b * PRIORS + p];
                selBox = sb;
                selArea = (sb.z - sb.x) * (sb.w - sb.y);
                float* o = out + ((size_t)b * TOPN + t) * 6;
                o[0] = fminf(fmaxf(db.x, 0.0f), 1.0f);
                o[1] = fminf(fmaxf(db.y, 0.0f), 1.0f);
                o[2] = fminf(fmaxf(db.z, 0.0f), 1.0f);
                o[3] = fminf(fmaxf(db.w, 0.0f), 1.0f);
                o[4] = fs;
                o[5] = (float)c;
            } else {
                stop = 1;
            }
        }
        __syncthreads();
        if (stop) {
            float* orow = out + ((size_t)b * TOPN + t) * 6;
            for (int k = tid; k < (TOPN - t) * 6; k += NMS_T) orow[k] = 0.0f;
            break;
        }
        const float4 sb = selBox; const float sa = selArea; const int fj = fjS;
        // ---- explicit owner clear (matches .at[i].set(-1); self-IoU would
        //      also catch it, but keep it exact). Compile-time reg indices. ----
#pragma unroll
        for (int k = 0; k < NMS_K; ++k)
            if (tid + k * NMS_T == fj) sreg[k] = -1.0f;
        // ---- suppression sweep: registers updated, boxes re-read (L2) ----
#pragma unroll
        for (int k = 0; k < NMS_K; ++k) {
            int j = tid + k * NMS_T;
            if (j < n) {
                float4 q = bx[j];
                float aj = (q.z - q.x) * (q.w - q.y);   // bit-identical to filter's area
                float ix1 = fmaxf(q.x, sb.x);
                float iy1 = fmaxf(q.y, sb.y);
                float ix2 = fminf(q.z, sb.z);
                float iy2 = fminf(q.w, sb.w);
                float inter = fmaxf(ix2 - ix1, 0.0f) * fmaxf(iy2 - iy1, 0.0f);
                float iou = inter / (aj + sa - inter);  // NaN > thr == false, like jnp
                if (iou > NMS_THR) sreg[k] = -1.0f;
            }
        }
        // no barrier needed: scores are thread-private
    }
}

// ---------------------------------------------------------------------------
extern "C" void kernel_launch(void* const* d_in, const int* in_sizes, int n_in,
                              void* d_out, int out_size, void* d_ws, size_t ws_size,
                              hipStream_t stream)
{
    const float* deltas = (const float*)d_in[0];
    const float* obj    = (const float*)d_in[1];
    const float* priors = (const float*)d_in[2];
    float* out = (float*)d_out;

    char* ws = (char*)d_ws;
    float* dec  = (float*)ws;                              // B*P*4 floats
    float* offA = dec + (size_t)BATCH * PRIORS * 4;        // B floats
    int*   cnt  = (int*)(offA + BATCH);                    // B ints
    size_t fixedBytes = ((size_t)BATCH * PRIORS * 4 + BATCH + BATCH) * 4;
    size_t candOff = (fixedBytes + 255) & ~(size_t)255;
    size_t avail = ws_size > candOff ? ws_size - candOff : 0;
    long cap = (long)(avail / ((size_t)BATCH * 24));       // 24 B / candidate
    if (cap > NMS_CAP) cap = NMS_CAP;
    if (cap < 1) cap = 1;

    float4* boxArr = (float4*)(ws + candOff);
    float*  sArr   = (float*)(boxArr + (size_t)BATCH * cap);
    int*    oidArr = (int*)(sArr + (size_t)BATCH * cap);

    decode_kernel<<<BATCH, 256, 0, stream>>>(deltas, priors, dec, offA, cnt);
    dim3 sg(NBLKX, BATCH, 1);
    score_filter_kernel<<<sg, 1024, 0, stream>>>(
        obj, dec, offA, cnt, sArr, boxArr, oidArr, (int)cap);
    nms_kernel<<<BATCH, NMS_T, 0, stream>>>(
        dec, cnt, sArr, boxArr, oidArr, out, (int)cap);
}

// Round 4
// 807.288 us; speedup vs baseline: 2.5628x; 2.5628x over previous
//
#include <hip/hip_runtime.h>
#include <cfloat>
#include <cstdint>

#define BATCH 16
#define PRIORS 3000
#define NCLS 201
#define NLBL 200           // NCLS - 1
#define TOPN 100
#define SCORE_THR 0.02f
#define NMS_THR 0.45f
#define PPB 16             // priors per block in score_filter (16 waves)
#define NBLKX ((PRIORS + PPB - 1) / PPB)   // 188

// NMS v4: packed u64 keys in registers. 1024 threads x 20 slots = 20480 cap
// (n ~= 17580 +- 130 -> +22 sigma margin). key[20] = 40 VGPRs, far under the
// 128-VGPR hard cap of a 16-wave block -> cannot spill (v3 lesson: 512x64
// needed 128 array VGPRs, compiler spilled to scratch -> 2x regression).
#define NMS_T 1024
#define NMS_K 20
#define NMS_CAP (NMS_T * NMS_K)

// key = (float_bits(prob) << 32) | (0xFFFFFFFF - oid)
//   u64 max == argmax by score, tie -> smaller oid == jnp.argmax first-index.
//   key==0 == suppressed/empty (all live scores > 0.02 > 0).

// ---------------------------------------------------------------------------
// Kernel A: decode boxes, per-image max coordinate (class-offset trick),
// zero per-image candidate counters.
// ---------------------------------------------------------------------------
__global__ __launch_bounds__(256) void decode_kernel(
    const float* __restrict__ deltas,   // [B][P][4]
    const float* __restrict__ priors,   // [P][4]
    float* __restrict__ dec,            // [B][P][4]  (x1,y1,x2,y2, un-offset)
    float* __restrict__ offA,           // [B]        max(dec)+1
    int*   __restrict__ cnt)            // [B]
{
    const int b = blockIdx.x;
    const int tid = threadIdx.x;
    float lmax = -FLT_MAX;
    for (int p = tid; p < PRIORS; p += 256) {
        float4 d4 = ((const float4*)deltas)[(size_t)b * PRIORS + p];
        float4 pr = ((const float4*)priors)[p];
        float cx = d4.x * 0.1f * pr.z + pr.x;
        float cy = d4.y * 0.1f * pr.w + pr.y;
        float w  = expf(d4.z * 0.2f) * pr.z;
        float h  = expf(d4.w * 0.2f) * pr.w;
        float x1 = cx - 0.5f * w, y1 = cy - 0.5f * h;
        float x2 = cx + 0.5f * w, y2 = cy + 0.5f * h;
        ((float4*)dec)[(size_t)b * PRIORS + p] = make_float4(x1, y1, x2, y2);
        lmax = fmaxf(lmax, fmaxf(fmaxf(x1, y1), fmaxf(x2, y2)));
    }
    for (int d = 32; d > 0; d >>= 1)
        lmax = fmaxf(lmax, __shfl_xor(lmax, d, 64));
    __shared__ float wmax[4];
    if ((tid & 63) == 0) wmax[tid >> 6] = lmax;
    __syncthreads();
    if (tid == 0) {
        float m = fmaxf(fmaxf(wmax[0], wmax[1]), fmaxf(wmax[2], wmax[3]));
        offA[b] = m + 1.0f;
        cnt[b] = 0;
    }
}

// ---------------------------------------------------------------------------
// Kernel B: block = 16 waves = 16 priors of ONE image. Per-wave softmax,
// LDS staging, ONE global atomicAdd per block (R1->R2: per-candidate global
// atomics were 300 ns each serialized -> 5.3 ms). Payload: u64 key + box.
// ---------------------------------------------------------------------------
__global__ __launch_bounds__(1024) void score_filter_kernel(
    const float*    __restrict__ obj,     // [B][P][NCLS]
    const float*    __restrict__ dec,     // [B][P][4]
    const float*    __restrict__ offA,    // [B]
    int*            __restrict__ cnt,     // [B]
    uint64_t*       __restrict__ keyArr,  // [B][cap]
    float4*         __restrict__ boxArr,  // [B][cap]  offset boxes
    int cap)
{
    __shared__ float lprob[PPB * NLBL];
    __shared__ uint32_t lpc[PPB * NLBL];  // (p<<8) | c
    __shared__ int lcnt;
    __shared__ int gbase;

    const int b    = blockIdx.y;
    const int tid  = threadIdx.x;
    const int wave = tid >> 6;
    const int lane = tid & 63;
    const int p    = blockIdx.x * PPB + wave;

    if (tid == 0) lcnt = 0;
    __syncthreads();

    if (p < PRIORS) {
        const float* x = obj + ((size_t)b * PRIORS + p) * NCLS;
        float v0 = x[lane];
        float v1 = x[lane + 64];
        float v2 = x[lane + 128];
        float v3 = (lane + 192 < NCLS) ? x[lane + 192] : -FLT_MAX;
        float mx = fmaxf(fmaxf(v0, v1), fmaxf(v2, v3));
        for (int d = 32; d > 0; d >>= 1) mx = fmaxf(mx, __shfl_xor(mx, d, 64));
        float e0 = expf(v0 - mx), e1 = expf(v1 - mx), e2 = expf(v2 - mx);
        float e3 = (lane + 192 < NCLS) ? expf(v3 - mx) : 0.0f;
        float se = e0 + e1 + e2 + e3;
        for (int d = 32; d > 0; d >>= 1) se += __shfl_xor(se, d, 64);
        float inv = 1.0f / se;
        float ev[4] = { e0, e1, e2, e3 };
#pragma unroll
        for (int k = 0; k < 4; ++k) {
            int c = lane + 64 * k;
            if (c >= 1 && c < NCLS) {
                float prob = ev[k] * inv;
                if (prob > SCORE_THR) {
                    int li = atomicAdd(&lcnt, 1);        // LDS atomic: cheap
                    lprob[li] = prob;
                    lpc[li]   = ((uint32_t)p << 8) | (uint32_t)c;
                }
            }
        }
    }
    __syncthreads();

    const int nloc = lcnt;
    if (tid == 0 && nloc > 0) gbase = atomicAdd(&cnt[b], nloc);
    __syncthreads();

    if (nloc > 0) {
        const int base = gbase;
        const float ofb = offA[b];
        for (int j = tid; j < nloc; j += 1024) {
            int idx = base + j;
            if (idx >= cap) continue;
            uint32_t pc = lpc[j];
            int pp = (int)(pc >> 8);
            int c  = (int)(pc & 0xff);
            float prob = lprob[j];
            float4 db = ((const float4*)dec)[(size_t)b * PRIORS + pp];
            float lo  = (float)c * ofb;
            uint32_t oid = (uint32_t)(pp * NLBL + (c - 1));
            size_t o = (size_t)b * cap + idx;
            keyArr[o] = ((uint64_t)__float_as_uint(prob) << 32)
                      | (uint64_t)(0xFFFFFFFFu - oid);
            boxArr[o] = make_float4(db.x + lo, db.y + lo, db.z + lo, db.w + lo);
        }
    }
}

// ---------------------------------------------------------------------------
// Kernel C (v4): one block per image; u64 keys in registers.
// Argmax: 20 register u64-max + wave shuffle reduce + 16-entry LDS reduce.
// Selected box recomputed from dec[p] + c*off (bit-identical to filter's
// construction). Owner suppressed by its own self-IoU == 1.0 (> 0.45);
// areas strictly positive, so this always fires -- matches .at[i].set(-1).
// Sweep: only live slots load their box (coalesced float4, L2-resident).
// ---------------------------------------------------------------------------
__global__ __launch_bounds__(NMS_T) void nms_kernel(
    const float*    __restrict__ dec,
    const int*      __restrict__ cnt,
    const uint64_t* __restrict__ keyArr,
    const float4*   __restrict__ boxArr,
    const float*    __restrict__ offA,
    float*          __restrict__ out,     // [B][TOPN][6]
    int cap)
{
    const int b = blockIdx.x;
    const int tid = threadIdx.x;
    int n = cnt[b]; if (n > cap) n = cap;
    const uint64_t* keys = keyArr + (size_t)b * cap;
    const float4*   bx   = boxArr + (size_t)b * cap;
    const float     ofb  = offA[b];

    uint64_t key[NMS_K];
#pragma unroll
    for (int k = 0; k < NMS_K; ++k) {
        int j = tid + k * NMS_T;
        key[k] = (j < n) ? keys[j] : 0ull;
    }

    __shared__ uint64_t rk[NMS_T / 64];
    __shared__ float4 sbS; __shared__ float saS;
    __shared__ uint64_t fkS;

    for (int t = 0; t < TOPN; ++t) {
        // ---- per-thread register argmax (u64 max) ----
        uint64_t bk = 0ull;
#pragma unroll
        for (int k = 0; k < NMS_K; ++k) bk = (key[k] > bk) ? key[k] : bk;
        // ---- wave shuffle reduce ----
        for (int d = 32; d > 0; d >>= 1) {
            uint64_t o = __shfl_xor((unsigned long long)bk, d, 64);
            bk = (o > bk) ? o : bk;
        }
        if ((tid & 63) == 0) rk[tid >> 6] = bk;
        __syncthreads();
        // ---- final reduce + selection bookkeeping (tid 0) ----
        if (tid == 0) {
            uint64_t fk = rk[0];
            for (int w = 1; w < NMS_T / 64; ++w) fk = (rk[w] > fk) ? rk[w] : fk;
            fkS = fk;
            if (fk) {
                uint32_t oid = 0xFFFFFFFFu - (uint32_t)fk;
                float fs = __uint_as_float((uint32_t)(fk >> 32));
                int p = (int)(oid / NLBL);
                int c = (int)(oid - (uint32_t)p * NLBL) + 1;
                float4 db = ((const float4*)dec)[(size_t)b * PRIORS + p];
                float lo = (float)c * ofb;                 // == filter's box, bit-exact
                float4 sb = make_float4(db.x + lo, db.y + lo, db.z + lo, db.w + lo);
                sbS = sb;
                saS = (sb.z - sb.x) * (sb.w - sb.y);
                float* o = out + ((size_t)b * TOPN + t) * 6;
                o[0] = fminf(fmaxf(db.x, 0.0f), 1.0f);
                o[1] = fminf(fmaxf(db.y, 0.0f), 1.0f);
                o[2] = fminf(fmaxf(db.z, 0.0f), 1.0f);
                o[3] = fminf(fmaxf(db.w, 0.0f), 1.0f);
                o[4] = fs;
                o[5] = (float)c;
            }
        }
        __syncthreads();
        if (fkS == 0ull) {
            float* orow = out + ((size_t)b * TOPN + t) * 6;
            for (int k = tid; k < (TOPN - t) * 6; k += NMS_T) orow[k] = 0.0f;
            break;
        }
        const float4 sb = sbS; const float sa = saS;
        // ---- suppression sweep: live slots only ----
#pragma unroll
        for (int k = 0; k < NMS_K; ++k) {
            if (key[k]) {
                int j = tid + k * NMS_T;
                float4 q = bx[j];
                float aj = (q.z - q.x) * (q.w - q.y);
                float ix1 = fmaxf(q.x, sb.x);
                float iy1 = fmaxf(q.y, sb.y);
                float ix2 = fminf(q.z, sb.z);
                float iy2 = fminf(q.w, sb.w);
                float inter = fmaxf(ix2 - ix1, 0.0f) * fmaxf(iy2 - iy1, 0.0f);
                float iou = inter / (aj + sa - inter);     // NaN>thr==false, like jnp
                if (iou > NMS_THR) key[k] = 0ull;
            }
        }
        // no barrier: keys are thread-private; LDS reuse guarded by the
        // two barriers above (writes for iter t+1 happen after barrier 2).
    }
}

// ---------------------------------------------------------------------------
extern "C" void kernel_launch(void* const* d_in, const int* in_sizes, int n_in,
                              void* d_out, int out_size, void* d_ws, size_t ws_size,
                              hipStream_t stream)
{
    const float* deltas = (const float*)d_in[0];
    const float* obj    = (const float*)d_in[1];
    const float* priors = (const float*)d_in[2];
    float* out = (float*)d_out;

    char* ws = (char*)d_ws;
    float* dec  = (float*)ws;                              // B*P*4 floats
    float* offA = dec + (size_t)BATCH * PRIORS * 4;        // B floats
    int*   cnt  = (int*)(offA + BATCH);                    // B ints
    size_t fixedBytes = ((size_t)BATCH * PRIORS * 4 + BATCH + BATCH) * 4;
    size_t candOff = (fixedBytes + 255) & ~(size_t)255;
    size_t avail = ws_size > candOff ? ws_size - candOff : 0;
    long cap = (long)(avail / ((size_t)BATCH * 24));       // 16 B box + 8 B key
    if (cap > NMS_CAP) cap = NMS_CAP;
    if (cap < 1) cap = 1;

    float4*   boxArr = (float4*)(ws + candOff);
    uint64_t* keyArr = (uint64_t*)(boxArr + (size_t)BATCH * cap);

    decode_kernel<<<BATCH, 256, 0, stream>>>(deltas, priors, dec, offA, cnt);
    dim3 sg(NBLKX, BATCH, 1);
    score_filter_kernel<<<sg, 1024, 0, stream>>>(
        obj, dec, offA, cnt, keyArr, boxArr, (int)cap);
    nms_kernel<<<BATCH, NMS_T, 0, stream>>>(
        dec, cnt, keyArr, boxArr, offA, out, (int)cap);
}

// Round 5
// 203.889 us; speedup vs baseline: 10.1474x; 3.9594x over previous
//
#include <hip/hip_runtime.h>
#include <cfloat>
#include <cstdint>

#define BATCH 16
#define PRIORS 3000
#define NCLS 201
#define NLBL 200           // NCLS - 1
#define TOPN 100
#define SCORE_THR 0.02f
#define NMS_THR 0.45f

// filter: 64 priors per 1024-thread block (16 waves x 4 priors each).
// R2 lesson: same-address global atomicAdd serializes at ~300 ns; 47 blocks
// per image counter -> ~14 us chain (was 188 -> ~56 us).
#define FPPB 64
#define FBLK ((PRIORS + FPPB - 1) / FPPB)   // 47
#define FCAP 4096          // LDS key staging (mean 376/block, +190 sigma)

// nms: sorted-scan. Greedy NMS == scan in descending full-key order,
// accept iff not suppressed by an earlier accept (picks are the only
// suppressors). Keys distinct (oid unique) -> total order == jnp.argmax
// semantics (score desc, first-index tie-break).
#define NMS_T 1024
#define NMS_CAP 20480      // per-image candidate cap (n ~= 17.6k +22 sigma)
#define NBINS 1024         // strata over (key>>48)-SB_BASE, natural range 0..733
#define CHUNK 2048         // bitonic chunk
#define SB_BASE 0x3CA3     // floatbits(0.02) >> 16

__device__ __forceinline__ int key_stratum(uint64_t k) {
    int s = (int)(k >> 48) - SB_BASE;           // prob in (0.02,1] -> [0,733]
    return s < 0 ? 0 : (s > NBINS - 1 ? NBINS - 1 : s);
}

// ---------------------------------------------------------------------------
// Kernel A: decode boxes, per-image max coordinate (class-offset trick),
// zero per-image candidate counters. (Arithmetic unchanged since R1 —
// bit-stable vs reference, absmax 0.0 across rounds.)
// ---------------------------------------------------------------------------
__global__ __launch_bounds__(256) void decode_kernel(
    const float* __restrict__ deltas,   // [B][P][4]
    const float* __restrict__ priors,   // [P][4]
    float* __restrict__ dec,            // [B][P][4]  (x1,y1,x2,y2, un-offset)
    float* __restrict__ offA,           // [B]        max(dec)+1
    int*   __restrict__ cnt)            // [B]
{
    const int b = blockIdx.x;
    const int tid = threadIdx.x;
    float lmax = -FLT_MAX;
    for (int p = tid; p < PRIORS; p += 256) {
        float4 d4 = ((const float4*)deltas)[(size_t)b * PRIORS + p];
        float4 pr = ((const float4*)priors)[p];
        float cx = d4.x * 0.1f * pr.z + pr.x;
        float cy = d4.y * 0.1f * pr.w + pr.y;
        float w  = expf(d4.z * 0.2f) * pr.z;
        float h  = expf(d4.w * 0.2f) * pr.w;
        float x1 = cx - 0.5f * w, y1 = cy - 0.5f * h;
        float x2 = cx + 0.5f * w, y2 = cy + 0.5f * h;
        ((float4*)dec)[(size_t)b * PRIORS + p] = make_float4(x1, y1, x2, y2);
        lmax = fmaxf(lmax, fmaxf(fmaxf(x1, y1), fmaxf(x2, y2)));
    }
    for (int d = 32; d > 0; d >>= 1)
        lmax = fmaxf(lmax, __shfl_xor(lmax, d, 64));
    __shared__ float wmax[4];
    if ((tid & 63) == 0) wmax[tid >> 6] = lmax;
    __syncthreads();
    if (tid == 0) {
        float m = fmaxf(fmaxf(wmax[0], wmax[1]), fmaxf(wmax[2], wmax[3]));
        offA[b] = m + 1.0f;
        cnt[b] = 0;
    }
}

// ---------------------------------------------------------------------------
// Kernel B: softmax + filter. Emits ONLY 8-byte keys:
//   key = (float_bits(prob) << 32) | (0xFFFFFFFF - oid),  oid = p*200+(c-1)
// Boxes are reconstructed in NMS from dec (bit-identical expressions).
// Softmax arithmetic identical to R2-R4 (bit-stable).
// ---------------------------------------------------------------------------
__global__ __launch_bounds__(1024) void score_filter_kernel(
    const float* __restrict__ obj,      // [B][P][NCLS]
    int*         __restrict__ cnt,      // [B]
    uint64_t*    __restrict__ keyArr,   // [B][cap]
    int cap)
{
    __shared__ uint64_t lkey[FCAP];
    __shared__ int lcnt;
    __shared__ int gbase;

    const int b    = blockIdx.y;
    const int tid  = threadIdx.x;
    const int wave = tid >> 6;
    const int lane = tid & 63;

    if (tid == 0) lcnt = 0;
    __syncthreads();

    for (int pp = 0; pp < FPPB / 16; ++pp) {
        int p = blockIdx.x * FPPB + wave * (FPPB / 16) + pp;
        if (p >= PRIORS) continue;                 // wave-uniform guard
        const float* x = obj + ((size_t)b * PRIORS + p) * NCLS;
        float v0 = x[lane];
        float v1 = x[lane + 64];
        float v2 = x[lane + 128];
        float v3 = (lane + 192 < NCLS) ? x[lane + 192] : -FLT_MAX;
        float mx = fmaxf(fmaxf(v0, v1), fmaxf(v2, v3));
        for (int d = 32; d > 0; d >>= 1) mx = fmaxf(mx, __shfl_xor(mx, d, 64));
        float e0 = expf(v0 - mx), e1 = expf(v1 - mx), e2 = expf(v2 - mx);
        float e3 = (lane + 192 < NCLS) ? expf(v3 - mx) : 0.0f;
        float se = e0 + e1 + e2 + e3;
        for (int d = 32; d > 0; d >>= 1) se += __shfl_xor(se, d, 64);
        float inv = 1.0f / se;
        float ev[4] = { e0, e1, e2, e3 };
#pragma unroll
        for (int k = 0; k < 4; ++k) {
            int c = lane + 64 * k;
            if (c >= 1 && c < NCLS) {
                float prob = ev[k] * inv;
                if (prob > SCORE_THR) {
                    uint32_t oid = (uint32_t)(p * NLBL + (c - 1));
                    uint64_t key = ((uint64_t)__float_as_uint(prob) << 32)
                                 | (uint64_t)(0xFFFFFFFFu - oid);
                    int li = atomicAdd(&lcnt, 1);
                    if (li < FCAP) {
                        lkey[li] = key;
                    } else {                        // exact spill path (never taken)
                        int gi = atomicAdd(&cnt[b], 1);
                        if (gi < cap) keyArr[(size_t)b * cap + gi] = key;
                    }
                }
            }
        }
    }
    __syncthreads();

    int nloc = lcnt; if (nloc > FCAP) nloc = FCAP;
    if (tid == 0 && nloc > 0) gbase = atomicAdd(&cnt[b], nloc);
    __syncthreads();

    if (nloc > 0) {
        const int base = gbase;
        for (int j = tid; j < nloc; j += 1024) {
            int idx = base + j;
            if (idx < cap) keyArr[(size_t)b * cap + idx] = lkey[j];
        }
    }
}

// ---------------------------------------------------------------------------
// Wave-0 scan step: test candidate `key` against accepted list; accept if
// no accepted box has IoU > 0.45 with it. Returns updated accept count.
// Box/area reconstructed bit-identically to the reference's bo/areas:
//   offset box = dec[p] + c*off ; area from offset coords.
// IoU operand order matches reference: max(cand,acc), denom cand+acc-inter.
// ---------------------------------------------------------------------------
__device__ __forceinline__ int scan_step_w0(
    uint64_t key, int b, const float4* __restrict__ dec4, float ofb,
    float4* abox, float* aarea, int na, float* __restrict__ out, int lane)
{
    uint32_t oid = 0xFFFFFFFFu - (uint32_t)key;
    int p = (int)(oid / NLBL);
    int c = (int)(oid - (uint32_t)p * NLBL) + 1;
    float4 db = dec4[(size_t)b * PRIORS + p];       // wave-uniform L2 load
    float lo = (float)c * ofb;
    float qx1 = db.x + lo, qy1 = db.y + lo;
    float qx2 = db.z + lo, qy2 = db.w + lo;
    float aq = (qx2 - qx1) * (qy2 - qy1);
    bool sup = false;
    for (int l = lane; l < na; l += 64) {
        float4 a = abox[l];
        float ix1 = fmaxf(qx1, a.x);
        float iy1 = fmaxf(qy1, a.y);
        float ix2 = fminf(qx2, a.z);
        float iy2 = fminf(qy2, a.w);
        float inter = fmaxf(ix2 - ix1, 0.0f) * fmaxf(iy2 - iy1, 0.0f);
        float iou = inter / (aq + aarea[l] - inter);   // NaN>thr==false, like jnp
        if (iou > NMS_THR) sup = true;
    }
    if (__ballot(sup) == 0ull) {
        if (lane == 0) {
            abox[na]  = make_float4(qx1, qy1, qx2, qy2);
            aarea[na] = aq;
            float* o = out + ((size_t)b * TOPN + na) * 6;
            o[0] = fminf(fmaxf(db.x, 0.0f), 1.0f);
            o[1] = fminf(fmaxf(db.y, 0.0f), 1.0f);
            o[2] = fminf(fmaxf(db.z, 0.0f), 1.0f);
            o[3] = fminf(fmaxf(db.w, 0.0f), 1.0f);
            o[4] = __uint_as_float((uint32_t)(key >> 32));
            o[5] = (float)c;
        }
        __threadfence_block();   // make abox/aarea store visible to wave lanes
        return na + 1;
    }
    return na;
}

// ---------------------------------------------------------------------------
// Kernel C (v5): one block per image. Strata histogram -> suffix counts ->
// chunked top-down processing: collect strata range (<=2048 keys), bitonic
// sort descending by full key in LDS, single-wave sorted scan (~105 visits
// expected before 100 accepts). Outer loop + argmax-extraction fallback for
// an overfull stratum guarantee exactness for arbitrary data.
// ---------------------------------------------------------------------------
__global__ __launch_bounds__(NMS_T) void nms_kernel(
    const float*    __restrict__ dec,
    const int*      __restrict__ cnt,
    const uint64_t* __restrict__ keyArr,
    const float*    __restrict__ offA,
    float*          __restrict__ out,     // [B][TOPN][6]
    int cap)
{
    __shared__ int      sufx[NBINS];      // hist -> inclusive suffix counts
    __shared__ uint64_t skey[CHUNK];
    __shared__ float4   abox[128];        // accepted offset boxes (<=100)
    __shared__ float    aarea[128];
    __shared__ uint64_t rk[NMS_T / 64];
    __shared__ int lcolS, loS, naS;
    __shared__ uint64_t fkS;

    const int b    = blockIdx.x;
    const int tid  = threadIdx.x;
    const int wave = tid >> 6;
    const int lane = tid & 63;
    int n = cnt[b]; if (n > cap) n = cap;
    const uint64_t* keys = keyArr + (size_t)b * cap;
    const float4*   dec4 = (const float4*)dec;
    const float     ofb  = offA[b];

    // ---- histogram over score strata ----
    sufx[tid] = 0;                         // NBINS == NMS_T
    if (tid == 0) naS = 0;
    __syncthreads();
    for (int j = tid; j < n; j += NMS_T)
        atomicAdd(&sufx[key_stratum(keys[j])], 1);
    __syncthreads();
    // ---- inclusive suffix sum (Hillis-Steele) ----
    for (int off = 1; off < NBINS; off <<= 1) {
        int v = (tid + off < NBINS) ? sufx[tid + off] : 0;
        __syncthreads();
        sufx[tid] += v;
        __syncthreads();
    }

    int curHi = NBINS;
    for (;;) {
        __syncthreads();
        int naCur = naS;
        int A = (curHi < NBINS) ? sufx[curHi] : 0;   // already-processed count
        int remaining = sufx[0] - A;
        if (naCur >= TOPN || remaining <= 0 || curHi <= 0) break;
        int target = A + CHUNK;
        // ---- find lo = smallest s with sufx[s] <= target (unique boundary) ----
        if (tid == 0) loS = curHi;
        __syncthreads();
        if (tid < curHi) {
            if (sufx[tid] <= target && (tid == 0 || sufx[tid - 1] > target))
                loS = tid;
        }
        __syncthreads();
        int lo = loS;

        if (lo < curHi) {
            // ---------------- chunk path (common) ----------------
            if (tid == 0) lcolS = 0;
            __syncthreads();
            for (int j = tid; j < n; j += NMS_T) {
                uint64_t k = keys[j];
                int s = key_stratum(k);
                if (s >= lo && s < curHi) {
                    int pos = atomicAdd(&lcolS, 1);
                    skey[pos] = k;                    // <= CHUNK guaranteed
                }
            }
            __syncthreads();
            int lcol = lcolS;
            for (int i = tid; i < CHUNK; i += NMS_T)
                if (i >= lcol) skey[i] = 0ull;
            // ---- bitonic sort, descending by full u64 key ----
            for (int k2 = 2; k2 <= CHUNK; k2 <<= 1) {
                for (int j2 = k2 >> 1; j2 > 0; j2 >>= 1) {
                    __syncthreads();
                    for (int ii = tid; ii < CHUNK; ii += NMS_T) {
                        int ixj = ii ^ j2;
                        if (ixj > ii) {
                            uint64_t a = skey[ii], bb = skey[ixj];
                            if (((ii & k2) == 0) ? (a < bb) : (a > bb)) {
                                skey[ii] = bb; skey[ixj] = a;
                            }
                        }
                    }
                }
            }
            __syncthreads();
            // ---- sorted scan on wave 0 ----
            if (wave == 0) {
                int nal = naS;
                for (int i = 0; i < lcol && nal < TOPN; ++i)
                    nal = scan_step_w0(skey[i], b, dec4, ofb, abox, aarea, nal, out, lane);
                if (lane == 0) naS = nal;
            }
            curHi = lo;
        } else {
            // ------- overfull stratum (>2048 same score-prefix; never with
            //         this data): exact extraction by repeated block argmax -------
            int s = curHi - 1;
            uint64_t lastK = ~0ull;
            for (;;) {
                __syncthreads();
                if (naS >= TOPN) break;
                uint64_t bk = 0ull;
                for (int j = tid; j < n; j += NMS_T) {
                    uint64_t k = keys[j];
                    if (key_stratum(k) == s && k < lastK && k > bk) bk = k;
                }
                for (int d = 32; d > 0; d >>= 1) {
                    uint64_t o = __shfl_xor((unsigned long long)bk, d, 64);
                    bk = (o > bk) ? o : bk;
                }
                if (lane == 0) rk[wave] = bk;
                __syncthreads();
                if (tid == 0) {
                    uint64_t fk = rk[0];
                    for (int w = 1; w < NMS_T / 64; ++w) fk = (rk[w] > fk) ? rk[w] : fk;
                    fkS = fk;
                }
                __syncthreads();
                uint64_t fk = fkS;
                if (fk == 0ull) break;
                if (wave == 0) {
                    int nal = naS;
                    nal = scan_step_w0(fk, b, dec4, ofb, abox, aarea, nal, out, lane);
                    if (lane == 0) naS = nal;
                }
                lastK = fk;
            }
            curHi = s;
        }
    }
    // ---- zero-fill rows naS..99 (harness poisons d_out) ----
    __syncthreads();
    int naF = naS;
    for (int idx = tid; idx < (TOPN - naF) * 6; idx += NMS_T)
        out[(size_t)b * TOPN * 6 + (size_t)naF * 6 + idx] = 0.0f;
}

// ---------------------------------------------------------------------------
extern "C" void kernel_launch(void* const* d_in, const int* in_sizes, int n_in,
                              void* d_out, int out_size, void* d_ws, size_t ws_size,
                              hipStream_t stream)
{
    const float* deltas = (const float*)d_in[0];
    const float* obj    = (const float*)d_in[1];
    const float* priors = (const float*)d_in[2];
    float* out = (float*)d_out;

    char* ws = (char*)d_ws;
    float* dec  = (float*)ws;                              // B*P*4 floats
    float* offA = dec + (size_t)BATCH * PRIORS * 4;        // B floats
    int*   cnt  = (int*)(offA + BATCH);                    // B ints
    size_t fixedBytes = ((size_t)BATCH * PRIORS * 4 + BATCH + BATCH) * 4;
    size_t candOff = (fixedBytes + 255) & ~(size_t)255;
    size_t avail = ws_size > candOff ? ws_size - candOff : 0;
    long cap = (long)(avail / ((size_t)BATCH * 8));        // 8 B key / candidate
    if (cap > NMS_CAP) cap = NMS_CAP;
    if (cap < 1) cap = 1;

    uint64_t* keyArr = (uint64_t*)(ws + candOff);

    decode_kernel<<<BATCH, 256, 0, stream>>>(deltas, priors, dec, offA, cnt);
    dim3 fg(FBLK, BATCH, 1);
    score_filter_kernel<<<fg, 1024, 0, stream>>>(obj, cnt, keyArr, (int)cap);
    nms_kernel<<<BATCH, NMS_T, 0, stream>>>(dec, cnt, keyArr, offA, out, (int)cap);
}

// Round 6
// 166.663 us; speedup vs baseline: 12.4140x; 1.2234x over previous
//
#include <hip/hip_runtime.h>
#include <cfloat>
#include <cstdint>

#define BATCH 16
#define PRIORS 3000
#define NCLS 201
#define NLBL 200           // NCLS - 1
#define TOPN 100
#define SCORE_THR 0.02f
#define NMS_THR 0.45f

// filter: 128 priors per 1024-thread block (16 waves x 8 priors each).
// R2 lesson: same-address global atomicAdd ~300 ns serialized; 24 blocks
// per image counter -> ~7 us chain (R5 was 47 -> ~14 us).
#define FPPB 128
#define FBLK ((PRIORS + FPPB - 1) / FPPB)   // 24
#define FCAP 8192          // LDS key staging (mean 750/block, +275 sigma)

// nms: sorted-scan. Greedy NMS == scan in descending full-key order,
// accept iff not suppressed by an earlier accept (picks are the only
// suppressors). Keys distinct (oid unique) -> total order == jnp.argmax
// semantics (score desc, first-index tie-break).
// key = (float_bits(prob) << 32) | (0xFFFFFFFF - oid), oid = p*200+(c-1).
#define NMS_T 1024
#define NMS_CAP 20480      // per-image candidate cap (n ~= 17.6k +22 sigma)
#define NBINS 1024         // strata over (key>>48)-SB_BASE, natural range 0..733
#define CHUNK 1024         // bitonic chunk (100th accept at sorted rank ~105)
#define SB_BASE 0x3CA3     // floatbits(0.02) >> 16

__device__ __forceinline__ int key_stratum(uint64_t k) {
    int s = (int)(k >> 48) - SB_BASE;           // prob in (0.02,1] -> [0,733]
    return s < 0 ? 0 : (s > NBINS - 1 ? NBINS - 1 : s);
}

// ---------------------------------------------------------------------------
// Kernel B: softmax + filter. Emits ONLY 8-byte keys. Boxes are
// reconstructed in NMS from an LDS-resident decode (bit-identical exprs).
// Softmax arithmetic identical to R2-R5 (bit-stable, absmax 0.0).
// ---------------------------------------------------------------------------
__global__ __launch_bounds__(1024) void score_filter_kernel(
    const float* __restrict__ obj,      // [B][P][NCLS]
    int*         __restrict__ cnt,      // [B]
    uint64_t*    __restrict__ keyArr,   // [B][cap]
    int cap)
{
    __shared__ uint64_t lkey[FCAP];
    __shared__ int lcnt;
    __shared__ int gbase;

    const int b    = blockIdx.y;
    const int tid  = threadIdx.x;
    const int wave = tid >> 6;
    const int lane = tid & 63;

    if (tid == 0) lcnt = 0;
    __syncthreads();

    for (int pp = 0; pp < FPPB / 16; ++pp) {
        int p = blockIdx.x * FPPB + wave * (FPPB / 16) + pp;
        if (p >= PRIORS) continue;                 // wave-uniform guard
        const float* x = obj + ((size_t)b * PRIORS + p) * NCLS;
        float v0 = x[lane];
        float v1 = x[lane + 64];
        float v2 = x[lane + 128];
        float v3 = (lane + 192 < NCLS) ? x[lane + 192] : -FLT_MAX;
        float mx = fmaxf(fmaxf(v0, v1), fmaxf(v2, v3));
        for (int d = 32; d > 0; d >>= 1) mx = fmaxf(mx, __shfl_xor(mx, d, 64));
        float e0 = expf(v0 - mx), e1 = expf(v1 - mx), e2 = expf(v2 - mx);
        float e3 = (lane + 192 < NCLS) ? expf(v3 - mx) : 0.0f;
        float se = e0 + e1 + e2 + e3;
        for (int d = 32; d > 0; d >>= 1) se += __shfl_xor(se, d, 64);
        float inv = 1.0f / se;
        float ev[4] = { e0, e1, e2, e3 };
#pragma unroll
        for (int k = 0; k < 4; ++k) {
            int c = lane + 64 * k;
            if (c >= 1 && c < NCLS) {
                float prob = ev[k] * inv;
                if (prob > SCORE_THR) {
                    uint32_t oid = (uint32_t)(p * NLBL + (c - 1));
                    uint64_t key = ((uint64_t)__float_as_uint(prob) << 32)
                                 | (uint64_t)(0xFFFFFFFFu - oid);
                    int li = atomicAdd(&lcnt, 1);
                    if (li < FCAP) {
                        lkey[li] = key;
                    } else {                        // exact spill path (never taken)
                        int gi = atomicAdd(&cnt[b], 1);
                        if (gi < cap) keyArr[(size_t)b * cap + gi] = key;
                    }
                }
            }
        }
    }
    __syncthreads();

    int nloc = lcnt; if (nloc > FCAP) nloc = FCAP;
    if (tid == 0 && nloc > 0) gbase = atomicAdd(&cnt[b], nloc);
    __syncthreads();

    if (nloc > 0) {
        const int base = gbase;
        for (int j = tid; j < nloc; j += 1024) {
            int idx = base + j;
            if (idx < cap) keyArr[(size_t)b * cap + idx] = lkey[j];
        }
    }
}

// ---------------------------------------------------------------------------
// Wave-0 scan step, ALL-LDS (R5 fix: per-visit global dec load was ~500 cyc
// x ~105 serial visits). Box/area reconstructed bit-identically to the
// reference's bo/areas: offset box = dec[p] + c*off; area from offset
// coords. IoU operand order matches reference.
// ---------------------------------------------------------------------------
__device__ __forceinline__ int scan_step_w0(
    uint64_t key, int b, const float4* __restrict__ dbox, float ofb,
    float4* abox, float* aarea, int na, float* __restrict__ out, int lane)
{
    uint32_t oid = 0xFFFFFFFFu - (uint32_t)key;
    int p = (int)(oid / NLBL);
    int c = (int)(oid - (uint32_t)p * NLBL) + 1;
    float4 db = dbox[p];                            // LDS broadcast
    float lo = (float)c * ofb;
    float qx1 = db.x + lo, qy1 = db.y + lo;
    float qx2 = db.z + lo, qy2 = db.w + lo;
    float aq = (qx2 - qx1) * (qy2 - qy1);
    bool sup = false;
    for (int l = lane; l < na; l += 64) {
        float4 a = abox[l];
        float ix1 = fmaxf(qx1, a.x);
        float iy1 = fmaxf(qy1, a.y);
        float ix2 = fminf(qx2, a.z);
        float iy2 = fminf(qy2, a.w);
        float inter = fmaxf(ix2 - ix1, 0.0f) * fmaxf(iy2 - iy1, 0.0f);
        float iou = inter / (aq + aarea[l] - inter);   // NaN>thr==false, like jnp
        if (iou > NMS_THR) sup = true;
    }
    if (__ballot(sup) == 0ull) {
        if (lane == 0) {
            abox[na]  = make_float4(qx1, qy1, qx2, qy2);
            aarea[na] = aq;
            float* o = out + ((size_t)b * TOPN + na) * 6;
            o[0] = fminf(fmaxf(db.x, 0.0f), 1.0f);
            o[1] = fminf(fmaxf(db.y, 0.0f), 1.0f);
            o[2] = fminf(fmaxf(db.z, 0.0f), 1.0f);
            o[3] = fminf(fmaxf(db.w, 0.0f), 1.0f);
            o[4] = __uint_as_float((uint32_t)(key >> 32));
            o[5] = (float)c;
        }
        __threadfence_block();   // abox/aarea visible to wave lanes
        return na + 1;
    }
    return na;
}

// ---------------------------------------------------------------------------
// Kernel C (v6): one block per image, decode FUSED (dec lives in LDS only).
// Phase 0: decode 3000 priors -> LDS dbox + block max -> off (exact: max is
//          order-invariant).
// Phase 1: strata histogram -> inclusive suffix counts.
// Phase 2: chunked top-down: collect strata range (<=1024 keys), bitonic
//          sort descending by full key, single-wave all-LDS sorted scan.
// Overfull-stratum argmax fallback keeps exactness for arbitrary data.
// ---------------------------------------------------------------------------
__global__ __launch_bounds__(NMS_T) void nms_kernel(
    const float*    __restrict__ deltas,  // [B][P][4]
    const float*    __restrict__ priors,  // [P][4]
    const int*      __restrict__ cnt,
    const uint64_t* __restrict__ keyArr,
    float*          __restrict__ out,     // [B][TOPN][6]
    int cap)
{
    __shared__ float4   dbox[PRIORS];     // 48 KB decoded boxes
    __shared__ int      sufx[NBINS];      // hist -> inclusive suffix counts
    __shared__ uint64_t skey[CHUNK];
    __shared__ float4   abox[112];        // accepted offset boxes (<=100)
    __shared__ float    aarea[112];
    __shared__ uint64_t rk[NMS_T / 64];
    __shared__ float    wred[NMS_T / 64];
    __shared__ int lcolS, loS, naS;
    __shared__ uint64_t fkS;
    __shared__ float ofbS;

    const int b    = blockIdx.x;
    const int tid  = threadIdx.x;
    const int wave = tid >> 6;
    const int lane = tid & 63;
    int n = cnt[b]; if (n > cap) n = cap;
    const uint64_t* keys = keyArr + (size_t)b * cap;

    // ---- Phase 0: decode into LDS + max reduce (exprs identical to R1-R5) ----
    float lmax = -FLT_MAX;
    for (int p = tid; p < PRIORS; p += NMS_T) {
        float4 d4 = ((const float4*)deltas)[(size_t)b * PRIORS + p];
        float4 pr = ((const float4*)priors)[p];
        float cx = d4.x * 0.1f * pr.z + pr.x;
        float cy = d4.y * 0.1f * pr.w + pr.y;
        float w  = expf(d4.z * 0.2f) * pr.z;
        float h  = expf(d4.w * 0.2f) * pr.w;
        float x1 = cx - 0.5f * w, y1 = cy - 0.5f * h;
        float x2 = cx + 0.5f * w, y2 = cy + 0.5f * h;
        dbox[p] = make_float4(x1, y1, x2, y2);
        lmax = fmaxf(lmax, fmaxf(fmaxf(x1, y1), fmaxf(x2, y2)));
    }
    for (int d = 32; d > 0; d >>= 1)
        lmax = fmaxf(lmax, __shfl_xor(lmax, d, 64));
    if (lane == 0) wred[wave] = lmax;
    // ---- Phase 1 init (same barrier) ----
    sufx[tid] = 0;                         // NBINS == NMS_T
    if (tid == 0) naS = 0;
    __syncthreads();
    if (tid == 0) {
        float m = wred[0];
        for (int w = 1; w < NMS_T / 64; ++w) m = fmaxf(m, wred[w]);
        ofbS = m + 1.0f;
    }
    // ---- histogram over score strata ----
    for (int j = tid; j < n; j += NMS_T)
        atomicAdd(&sufx[key_stratum(keys[j])], 1);
    __syncthreads();
    // ---- inclusive suffix sum (Hillis-Steele) ----
    for (int off = 1; off < NBINS; off <<= 1) {
        int v = (tid + off < NBINS) ? sufx[tid + off] : 0;
        __syncthreads();
        sufx[tid] += v;
        __syncthreads();
    }
    const float ofb = ofbS;

    int curHi = NBINS;
    for (;;) {
        __syncthreads();
        int naCur = naS;
        int A = (curHi < NBINS) ? sufx[curHi] : 0;   // already-processed count
        int remaining = sufx[0] - A;
        if (naCur >= TOPN || remaining <= 0 || curHi <= 0) break;
        int target = A + CHUNK;
        // ---- find lo = smallest s with sufx[s] <= target ----
        if (tid == 0) loS = curHi;
        __syncthreads();
        if (tid < curHi) {
            if (sufx[tid] <= target && (tid == 0 || sufx[tid - 1] > target))
                loS = tid;
        }
        __syncthreads();
        int lo = loS;

        if (lo < curHi) {
            // ---------------- chunk path (common) ----------------
            if (tid == 0) lcolS = 0;
            __syncthreads();
            for (int j = tid; j < n; j += NMS_T) {
                uint64_t k = keys[j];
                int s = key_stratum(k);
                if (s >= lo && s < curHi) {
                    int pos = atomicAdd(&lcolS, 1);
                    skey[pos] = k;                    // <= CHUNK guaranteed
                }
            }
            __syncthreads();
            int lcol = lcolS;
            if (tid >= lcol) skey[tid] = 0ull;        // CHUNK == NMS_T
            // ---- bitonic sort, descending by full u64 key ----
            for (int k2 = 2; k2 <= CHUNK; k2 <<= 1) {
                for (int j2 = k2 >> 1; j2 > 0; j2 >>= 1) {
                    __syncthreads();
                    int ixj = tid ^ j2;
                    if (ixj > tid) {
                        uint64_t a = skey[tid], bb = skey[ixj];
                        if (((tid & k2) == 0) ? (a < bb) : (a > bb)) {
                            skey[tid] = bb; skey[ixj] = a;
                        }
                    }
                }
            }
            __syncthreads();
            // ---- sorted scan on wave 0 (all-LDS) ----
            if (wave == 0) {
                int nal = naS;
                for (int i = 0; i < lcol && nal < TOPN; ++i)
                    nal = scan_step_w0(skey[i], b, dbox, ofb, abox, aarea, nal, out, lane);
                if (lane == 0) naS = nal;
            }
            curHi = lo;
        } else {
            // ------- overfull stratum (>1024 same score-prefix; never with
            //         this data): exact extraction by repeated block argmax -------
            int s = curHi - 1;
            uint64_t lastK = ~0ull;
            for (;;) {
                __syncthreads();
                if (naS >= TOPN) break;
                uint64_t bk = 0ull;
                for (int j = tid; j < n; j += NMS_T) {
                    uint64_t k = keys[j];
                    if (key_stratum(k) == s && k < lastK && k > bk) bk = k;
                }
                for (int d = 32; d > 0; d >>= 1) {
                    uint64_t o = __shfl_xor((unsigned long long)bk, d, 64);
                    bk = (o > bk) ? o : bk;
                }
                if (lane == 0) rk[wave] = bk;
                __syncthreads();
                if (tid == 0) {
                    uint64_t fk = rk[0];
                    for (int w = 1; w < NMS_T / 64; ++w) fk = (rk[w] > fk) ? rk[w] : fk;
                    fkS = fk;
                }
                __syncthreads();
                uint64_t fk = fkS;
                if (fk == 0ull) break;
                if (wave == 0) {
                    int nal = naS;
                    nal = scan_step_w0(fk, b, dbox, ofb, abox, aarea, nal, out, lane);
                    if (lane == 0) naS = nal;
                }
                lastK = fk;
            }
            curHi = s;
        }
    }
    // ---- zero-fill rows naS..99 (harness poisons d_out) ----
    __syncthreads();
    int naF = naS;
    for (int idx = tid; idx < (TOPN - naF) * 6; idx += NMS_T)
        out[(size_t)b * TOPN * 6 + (size_t)naF * 6 + idx] = 0.0f;
}

// ---------------------------------------------------------------------------
extern "C" void kernel_launch(void* const* d_in, const int* in_sizes, int n_in,
                              void* d_out, int out_size, void* d_ws, size_t ws_size,
                              hipStream_t stream)
{
    const float* deltas = (const float*)d_in[0];
    const float* obj    = (const float*)d_in[1];
    const float* priors = (const float*)d_in[2];
    float* out = (float*)d_out;

    char* ws = (char*)d_ws;
    int* cnt = (int*)ws;                                   // B ints
    size_t candOff = 256;
    size_t avail = ws_size > candOff ? ws_size - candOff : 0;
    long cap = (long)(avail / ((size_t)BATCH * 8));        // 8 B key / candidate
    if (cap > NMS_CAP) cap = NMS_CAP;
    if (cap < 1) cap = 1;
    uint64_t* keyArr = (uint64_t*)(ws + candOff);

    hipMemsetAsync(cnt, 0, BATCH * sizeof(int), stream);
    dim3 fg(FBLK, BATCH, 1);
    score_filter_kernel<<<fg, 1024, 0, stream>>>(obj, cnt, keyArr, (int)cap);
    nms_kernel<<<BATCH, NMS_T, 0, stream>>>(deltas, priors, cnt, keyArr, out, (int)cap);
}